// Round 3
// baseline (109.893 us; speedup 1.0000x reference)
//
#include <hip/hip_runtime.h>
#include <math.h>

namespace {

constexpr int D = 32;
constexpr int KOBJ = 1023;          // objects 1..1023 (cluster id 0 = noise)
constexpr float QMIN = 0.01f;
constexpr float PTT = 0.9f;
constexpr float METAETA = 4.0f;

typedef __attribute__((ext_vector_type(8))) short short8;
typedef __attribute__((ext_vector_type(4))) float f32x4;

__device__ inline float waveSum(float v) {
#pragma unroll
  for (int o = 32; o > 0; o >>= 1) v += __shfl_down(v, o, 64);
  return v;
}

// f32 -> bf16 round-to-nearest-even, as raw ushort bits
__device__ inline ushort f2bf(float f) {
  unsigned u = __float_as_uint(f);
  return (ushort)((u + 0x7FFFu + ((u >> 16) & 1u)) >> 16);
}

// ws accumulators: acc[0]=attSum acc[1]=repSum acc[2]=noiseSum acc[3]=noiseCnt
//                  acc[4]=hitOkCnt acc[5]=cowardSum
__global__ void k_init(float* acc, unsigned* cnt, int* flagNZ,
                       unsigned long long* keys, const int* __restrict__ cidw,
                       int N) {
  int i = blockIdx.x * blockDim.x + threadIdx.x;
  if (i < KOBJ) keys[i] = 0ull;
  if (i < 8) acc[i] = 0.f;
  if (i == 8) cnt[0] = 0u;
  if (i == 9) cnt[1] = 0u;
  if (blockIdx.x == 0) {
    if (threadIdx.x == 0) flagNZ[0] = 0;
    __syncthreads();
    // dtype detect: int64 cluster_ids (values 0..1023) => odd 32-bit words all 0
    for (int jj = threadIdx.x; jj < 1024; jj += blockDim.x) {
      int idx = 2 * jj + 1;
      if (idx < N && cidw[idx] != 0) flagNZ[0] = 1;  // benign same-value race
    }
  }
}

// per-hit pass + (last block) per-object gather
__global__ __launch_bounds__(256) void k_hits_cl(
    const float* __restrict__ beta, const float* __restrict__ x,
    const float* __restrict__ pt, const float* __restrict__ eta,
    const int* __restrict__ recon, const int* __restrict__ cidw,
    int N, const int* __restrict__ flagNZ,
    float* acc, unsigned* cnt, unsigned long long* keys,
    float* __restrict__ qArr, float* __restrict__ nxArr,
    int* __restrict__ attkArr, int* __restrict__ alphaArr,
    float2* __restrict__ qnk, ushort* __restrict__ xkb) {
  int t = threadIdx.x;
  int j = blockIdx.x * 256 + t;
  int is64 = (flagNZ[0] == 0);
  bool ok = false;
  if (j < N) {
    int cid = is64 ? cidw[2 * j] : cidw[j];
    float b = beta[j];
    float bc = fminf(fmaxf(b, 0.f), 1.f - 1e-4f);
    float tt = atanhf(bc);
    float q = tt * tt + QMIN;
    ok = (recon[j] > 0) && (pt[j] > PTT) && (fabsf(eta[j]) < METAETA);
    float nx = 0.f;
    const float4* xr = (const float4*)(x + (size_t)j * D);
#pragma unroll
    for (int i2 = 0; i2 < 8; ++i2) {
      float4 v = xr[i2];
      nx += v.x * v.x + v.y * v.y + v.z * v.z + v.w * v.w;
    }
    int attk = (ok && cid >= 1) ? cid : 0;
    qArr[j] = q;
    nxArr[j] = nx;
    attkArr[j] = attk;
    if (cid <= 0) {  // noise hit
      atomicAdd(&acc[2], b);
      atomicAdd(&acc[3], 1.f);
    }
    if (attk >= 1) {
      unsigned long long key =
          (((unsigned long long)__float_as_uint(q)) << 32) |
          (unsigned long long)(0xFFFFFFFFu - (unsigned)j);
      atomicMax(&keys[attk - 1], key);
    }
  }
  unsigned long long bal = __ballot(ok);
  if ((t & 63) == 0 && bal)
    atomicAdd(&acc[4], (float)__popcll(bal));

  // ---- last-block hand-off: per-object gather (was k_clusters) ----
  __threadfence();  // release our plain stores (qArr/nxArr/attkArr)
  __shared__ int lastFlag;
  if (t == 0) {
    unsigned tk = atomicAdd(&cnt[0], 1u);
    lastFlag = (tk == gridDim.x - 1);
  }
  __syncthreads();
  if (!lastFlag) return;
  __threadfence();  // acquire all blocks' writes

  float cw = 0.f;
  for (int k = t; k < 1024; k += 256) {
    if (k < KOBJ) {
      unsigned long long key = keys[k];
      int alpha = (key != 0ull) ? (int)(0xFFFFFFFFu - (unsigned)(key & 0xFFFFFFFFull)) : 0;
      alphaArr[k] = alpha;
      qnk[k] = make_float2(qArr[alpha], nxArr[alpha]);
      const float4* s4 = (const float4*)(x + (size_t)alpha * D);
      ushort* dst = xkb + (size_t)k * D;
#pragma unroll
      for (int i = 0; i < 8; ++i) {
        float4 v = s4[i];
        dst[4 * i + 0] = f2bf(v.x);
        dst[4 * i + 1] = f2bf(v.y);
        dst[4 * i + 2] = f2bf(v.z);
        dst[4 * i + 3] = f2bf(v.w);
      }
      cw += 1.f - beta[alpha];
    } else {  // pad column 1023: never passes d2<1
      qnk[k] = make_float2(0.f, 1e30f);
      ushort* dst = xkb + (size_t)k * D;
#pragma unroll
      for (int i = 0; i < D; ++i) dst[i] = 0;
    }
  }
  float s = waveSum(cw);
  if ((t & 63) == 0 && s != 0.f) atomicAdd(&acc[5], s);
}

// rep sweep (64 hits x 1024 objects per block) + own-rows att term
// + (last block) final reduction
__global__ __launch_bounds__(256) void k_pair_all(
    const float* __restrict__ x, int N,
    const float* __restrict__ qArr, const float* __restrict__ nxArr,
    const int* __restrict__ attkArr, const int* __restrict__ alphaArr,
    const float2* __restrict__ qnk, const ushort* __restrict__ xkb,
    float* acc, unsigned* cnt, float* out) {
  __shared__ float2 qnkS[1024];
  __shared__ int lastFlag;
  int t = threadIdx.x;
  for (int i = t; i < 1024; i += 256) qnkS[i] = qnk[i];

  int wv = t >> 6;          // wave -> object quarter
  int ln = t & 63;
  int lr = ln & 15;         // frag row (A) / col (B,C) selector
  int lk = ln >> 4;         // k-slice / acc-row-group selector
  int rowbase = blockIdx.x * 64;

  // A fragments: bf16(-2 * x_row), 4 row-tiles of 16 hits
  short8 am2[4];
#pragma unroll
  for (int rt = 0; rt < 4; ++rt) {
    int row = min(rowbase + rt * 16 + lr, N - 1);  // clamp; pads disabled via nxr
    const float* p = x + (size_t)row * D + lk * 8;
    float4 v0 = *(const float4*)p;
    float4 v1 = *(const float4*)(p + 4);
    short8 a;
    a[0] = (short)f2bf(-2.f * v0.x); a[1] = (short)f2bf(-2.f * v0.y);
    a[2] = (short)f2bf(-2.f * v0.z); a[3] = (short)f2bf(-2.f * v0.w);
    a[4] = (short)f2bf(-2.f * v1.x); a[5] = (short)f2bf(-2.f * v1.y);
    a[6] = (short)f2bf(-2.f * v1.z); a[7] = (short)f2bf(-2.f * v1.w);
    am2[rt] = a;
  }
  // per-acc-row norms and charges; C-row i of tile rt = rowbase+rt*16+lk*4+i
  float nxr[4][4], qrow[4][4];
#pragma unroll
  for (int rt = 0; rt < 4; ++rt)
#pragma unroll
    for (int i = 0; i < 4; ++i) {
      int row = rowbase + rt * 16 + lk * 4 + i;
      int rc = min(row, N - 1);
      nxr[rt][i] = (row < N) ? nxArr[rc] : 1e37f;
      qrow[rt][i] = (row < N) ? qArr[rc] : 0.f;
    }
  __syncthreads();

  float rep = 0.f;
  int objbase = wv * 256;
#pragma unroll 1
  for (int tt = 0; tt < 16; ++tt) {
    int obj = objbase + tt * 16 + lr;
    const short8 b = *(const short8*)(xkb + (size_t)obj * D + lk * 8);
    float2 qn = qnkS[obj];
    float nk = qn.y;
    // C init = nx_row + nx_k  =>  MFMA result s = nx_row + nx_k - 2*dot = d2
    f32x4 c0 = {nxr[0][0] + nk, nxr[0][1] + nk, nxr[0][2] + nk, nxr[0][3] + nk};
    f32x4 c1 = {nxr[1][0] + nk, nxr[1][1] + nk, nxr[1][2] + nk, nxr[1][3] + nk};
    f32x4 c2 = {nxr[2][0] + nk, nxr[2][1] + nk, nxr[2][2] + nk, nxr[2][3] + nk};
    f32x4 c3 = {nxr[3][0] + nk, nxr[3][1] + nk, nxr[3][2] + nk, nxr[3][3] + nk};
    f32x4 s0 = __builtin_amdgcn_mfma_f32_16x16x32_bf16(am2[0], b, c0, 0, 0, 0);
    f32x4 s1 = __builtin_amdgcn_mfma_f32_16x16x32_bf16(am2[1], b, c1, 0, 0, 0);
    f32x4 s2 = __builtin_amdgcn_mfma_f32_16x16x32_bf16(am2[2], b, c2, 0, 0, 0);
    f32x4 s3 = __builtin_amdgcn_mfma_f32_16x16x32_bf16(am2[3], b, c3, 0, 0, 0);
    float m = 1e30f;
#pragma unroll
    for (int i = 0; i < 4; ++i) {
      m = fminf(m, fminf(fminf(s0[i], s1[i]), fminf(s2[i], s3[i])));
    }
    if (__any(m < 1.f)) {  // rare: some pair within unit distance
      float qk = qn.x;
#pragma unroll
      for (int rt = 0; rt < 4; ++rt) {
#pragma unroll
        for (int i = 0; i < 4; ++i) {
          float d2 = (rt == 0) ? s0[i] : (rt == 1) ? s1[i] : (rt == 2) ? s2[i] : s3[i];
          if (d2 < 1.f)
            rep += qrow[rt][i] * qk * (1.f - sqrtf(fmaxf(d2, 1e-12f)));
        }
      }
    }
  }
  float sw = waveSum(rep);
  if (ln == 0 && sw != 0.f) atomicAdd(&acc[1], sw);

  // ---- exact f32 attractive term for this block's own 64 rows (wave 0) ----
  if (t < 64) {
    int j = rowbase + t;
    float attc = 0.f, repSub = 0.f;
    if (j < N) {
      int attk = attkArr[j];
      if (attk >= 1) {
        int k0 = attk - 1;
        int alpha = alphaArr[k0];
        float2 qn = qnk[k0];  // exact f32 (q_k, nx_k)
        const float4* xj = (const float4*)(x + (size_t)j * D);
        const float4* xk = (const float4*)(x + (size_t)alpha * D);
        float dot = 0.f;
#pragma unroll
        for (int i = 0; i < 8; ++i) {
          float4 a = xj[i], bb = xk[i];
          dot += a.x * bb.x + a.y * bb.y + a.z * bb.z + a.w * bb.w;
        }
        float d2 = nxArr[j] + qn.y - 2.f * dot;
        float w = qArr[j] * qn.x;
        attc = w * fmaxf(d2, 1e-12f);
        if (d2 < 1.f)  // att pair was counted by the rep sweep: subtract
          repSub = w * (1.f - sqrtf(fmaxf(d2, 1e-12f)));
      }
    }
    float sa = waveSum(attc);
    float sr = waveSum(repSub);
    if (t == 0) {
      if (sa != 0.f) atomicAdd(&acc[0], sa);
      if (sr != 0.f) atomicAdd(&acc[1], -sr);
    }
  }

  // ---- last-block hand-off: final scalar reduction (was k_final) ----
  __threadfence();
  if (t == 0) {
    unsigned tk = atomicAdd(&cnt[1], 1u);
    lastFlag = (tk == gridDim.x - 1);
  }
  __syncthreads();
  if (!lastFlag) return;
  __threadfence();
  if (t == 0) {
    double attSum = acc[0], repSum = acc[1], noiseSum = acc[2];
    double noiseCnt = acc[3], okCnt = acc[4], cowardSum = acc[5];
    double norm_att = 1e-9 + okCnt - (double)KOBJ;
    double norm_rep = 1e-9 + (double)(KOBJ - 1) * (double)N;
    double v_att = attSum / norm_att;
    double v_rep = repSum / norm_rep;
    double l_coward = cowardSum / (double)KOBJ;
    double l_noise = noiseSum / fmax(noiseCnt, 1.0);
    out[0] = (float)(v_att + 1.0 * v_rep + 0.1 * l_noise + 0.1 * l_coward);
  }
}

}  // namespace

extern "C" void kernel_launch(void* const* d_in, const int* in_sizes, int n_in,
                              void* d_out, int out_size, void* d_ws, size_t ws_size,
                              hipStream_t stream) {
  const float* beta = (const float*)d_in[0];
  const float* x = (const float*)d_in[1];
  const float* pt = (const float*)d_in[2];
  const float* eta = (const float*)d_in[3];
  const int* recon = (const int*)d_in[4];
  const int* cidw = (const int*)d_in[5];  // int32 or int64 layout, device-detected
  int N = in_sizes[0];
  float* out = (float*)d_out;

  char* w = (char*)d_ws;
  float* acc = (float*)w;                                   // 8 f32
  unsigned* cnt = (unsigned*)(w + 32);                      // 2 tickets
  int* flagNZ = (int*)(w + 40);
  unsigned long long* keys = (unsigned long long*)(w + 64); // 1023*8
  int* alphaArr = (int*)(w + 8256);                         // 1023*4
  float2* qnk = (float2*)(w + 12352);                       // 1024*8
  ushort* xkb = (ushort*)(w + 20544);                       // 1024*32*2 = 65536
  float* qArr = (float*)(w + 86080);                        // N*4
  float* nxArr = (float*)(w + 86080 + (size_t)N * 4);       // N*4
  int* attkArr = (int*)(w + 86080 + (size_t)N * 8);         // N*4

  int nbN = (N + 255) / 256;
  int rowgroups = (N + 63) / 64;

  k_init<<<4, 256, 0, stream>>>(acc, cnt, flagNZ, keys, cidw, N);
  k_hits_cl<<<nbN, 256, 0, stream>>>(beta, x, pt, eta, recon, cidw, N, flagNZ,
                                     acc, cnt, keys, qArr, nxArr, attkArr,
                                     alphaArr, qnk, xkb);
  k_pair_all<<<rowgroups, 256, 0, stream>>>(x, N, qArr, nxArr, attkArr,
                                            alphaArr, qnk, xkb, acc, cnt, out);
}

// Round 4
// 65.557 us; speedup vs baseline: 1.6763x; 1.6763x over previous
//
#include <hip/hip_runtime.h>
#include <math.h>

namespace {

constexpr int D = 32;
constexpr int KOBJ = 1023;          // objects 1..1023 (cluster id 0 = noise)
constexpr float QMIN = 0.01f;
constexpr float PTT = 0.9f;
constexpr float METAETA = 4.0f;

typedef __attribute__((ext_vector_type(8))) short short8;
typedef __attribute__((ext_vector_type(4))) float f32x4;

__device__ inline float waveSum(float v) {
#pragma unroll
  for (int o = 32; o > 0; o >>= 1) v += __shfl_down(v, o, 64);
  return v;
}

// f32 -> bf16 round-to-nearest-even, as raw ushort bits
__device__ inline ushort f2bf(float f) {
  unsigned u = __float_as_uint(f);
  return (ushort)((u + 0x7FFFu + ((u >> 16) & 1u)) >> 16);
}

// ws accumulators: acc[0]=attSum acc[1]=repSum acc[2]=noiseSum acc[3]=noiseCnt
//                  acc[4]=hitOkCnt acc[5]=cowardSum
__global__ void k_init(float* acc, int* flagNZ, unsigned long long* keys,
                       const int* __restrict__ cidw, int N) {
  int i = blockIdx.x * blockDim.x + threadIdx.x;
  if (i < KOBJ) keys[i] = 0ull;
  if (i < 8) acc[i] = 0.f;
  if (blockIdx.x == 0) {
    if (threadIdx.x == 0) flagNZ[0] = 0;
    __syncthreads();
    // dtype detect: int64 cluster_ids (values 0..1023) => odd 32-bit words all 0
    for (int jj = threadIdx.x; jj < 1024; jj += blockDim.x) {
      int idx = 2 * jj + 1;
      if (idx < N && cidw[idx] != 0) flagNZ[0] = 1;  // benign same-value race
    }
  }
}

__global__ __launch_bounds__(256) void k_hits(
    const float* __restrict__ beta, const float* __restrict__ x,
    const float* __restrict__ pt, const float* __restrict__ eta,
    const int* __restrict__ recon, const int* __restrict__ cidw,
    int N, const int* __restrict__ flagNZ,
    float* acc, unsigned long long* keys,
    float* __restrict__ qArr, float* __restrict__ nxArr,
    int* __restrict__ attkArr) {
  int t = threadIdx.x;
  int j = blockIdx.x * 256 + t;
  int is64 = (flagNZ[0] == 0);
  bool ok = false;
  if (j < N) {
    int cid = is64 ? cidw[2 * j] : cidw[j];
    float b = beta[j];
    float bc = fminf(fmaxf(b, 0.f), 1.f - 1e-4f);
    float tt = atanhf(bc);
    float q = tt * tt + QMIN;
    ok = (recon[j] > 0) && (pt[j] > PTT) && (fabsf(eta[j]) < METAETA);
    float nx = 0.f;
    const float4* xr = (const float4*)(x + (size_t)j * D);
#pragma unroll
    for (int i2 = 0; i2 < 8; ++i2) {
      float4 v = xr[i2];
      nx += v.x * v.x + v.y * v.y + v.z * v.z + v.w * v.w;
    }
    int attk = (ok && cid >= 1) ? cid : 0;
    qArr[j] = q;
    nxArr[j] = nx;
    attkArr[j] = attk;
    if (cid <= 0) {  // noise hit
      atomicAdd(&acc[2], b);
      atomicAdd(&acc[3], 1.f);
    }
    if (attk >= 1) {
      unsigned long long key =
          (((unsigned long long)__float_as_uint(q)) << 32) |
          (unsigned long long)(0xFFFFFFFFu - (unsigned)j);
      atomicMax(&keys[attk - 1], key);
    }
  }
  unsigned long long bal = __ballot(ok);
  if ((t & 63) == 0 && bal)
    atomicAdd(&acc[4], (float)__popcll(bal));
}

// per object: gather alpha, write qnk (q_k, nx_k) and bf16 embedding row
__global__ void k_clusters(const float* __restrict__ beta, const float* __restrict__ x,
                           const unsigned long long* __restrict__ keys,
                           const float* __restrict__ qArr, const float* __restrict__ nxArr,
                           int* __restrict__ alphaArr, float2* __restrict__ qnk,
                           ushort* __restrict__ xkb, float* acc) {
  int k = blockIdx.x * blockDim.x + threadIdx.x;
  float cw = 0.f;
  if (k < KOBJ) {
    unsigned long long key = keys[k];
    int alpha = (key != 0ull) ? (int)(0xFFFFFFFFu - (unsigned)(key & 0xFFFFFFFFull)) : 0;
    alphaArr[k] = alpha;
    qnk[k] = make_float2(qArr[alpha], nxArr[alpha]);
    const float4* s4 = (const float4*)(x + (size_t)alpha * D);
    ushort* dst = xkb + (size_t)k * D;
#pragma unroll
    for (int i = 0; i < 8; ++i) {
      float4 v = s4[i];
      dst[4 * i + 0] = f2bf(v.x);
      dst[4 * i + 1] = f2bf(v.y);
      dst[4 * i + 2] = f2bf(v.z);
      dst[4 * i + 3] = f2bf(v.w);
    }
    cw = 1.f - beta[alpha];
  } else if (k == KOBJ) {  // pad column 1023: never passes d2<1
    qnk[k] = make_float2(0.f, 1e30f);
    ushort* dst = xkb + (size_t)k * D;
#pragma unroll
    for (int i = 0; i < D; ++i) dst[i] = 0;
  }
  float s = waveSum(cw);
  if ((threadIdx.x & 63) == 0 && s != 0.f) atomicAdd(&acc[5], s);
}

// rep sweep (64 hits x 1024 objects per block) + own-rows exact att term.
// A = bf16(-2x), C = nx_row + nx_k  =>  MFMA output is d2 directly.
// Depth-1 software pipeline on the B fragment + qnk (fixes round-2/3 stall).
__global__ __launch_bounds__(256) void k_pair(
    const float* __restrict__ x, int N,
    const float* __restrict__ qArr, const float* __restrict__ nxArr,
    const int* __restrict__ attkArr, const int* __restrict__ alphaArr,
    const float2* __restrict__ qnk, const ushort* __restrict__ xkb,
    float* acc) {
  __shared__ float2 qnkS[1024];
  int t = threadIdx.x;
  for (int i = t; i < 1024; i += 256) qnkS[i] = qnk[i];

  int wv = t >> 6;          // wave -> object quarter
  int ln = t & 63;
  int lr = ln & 15;         // frag row (A) / col (B,C) selector
  int lk = ln >> 4;         // k-slice / acc-row-group selector
  int rowbase = blockIdx.x * 64;

  // A fragments: bf16(-2 * x_row), 4 row-tiles of 16 hits
  short8 am2[4];
#pragma unroll
  for (int rt = 0; rt < 4; ++rt) {
    int row = min(rowbase + rt * 16 + lr, N - 1);  // clamp; pads disabled via nxr
    const float* p = x + (size_t)row * D + lk * 8;
    float4 v0 = *(const float4*)p;
    float4 v1 = *(const float4*)(p + 4);
    short8 a;
    a[0] = (short)f2bf(-2.f * v0.x); a[1] = (short)f2bf(-2.f * v0.y);
    a[2] = (short)f2bf(-2.f * v0.z); a[3] = (short)f2bf(-2.f * v0.w);
    a[4] = (short)f2bf(-2.f * v1.x); a[5] = (short)f2bf(-2.f * v1.y);
    a[6] = (short)f2bf(-2.f * v1.z); a[7] = (short)f2bf(-2.f * v1.w);
    am2[rt] = a;
  }
  // per-acc-row norms and charges; C-row i of tile rt = rowbase+rt*16+lk*4+i
  float nxr[4][4], qrow[4][4];
#pragma unroll
  for (int rt = 0; rt < 4; ++rt)
#pragma unroll
    for (int i = 0; i < 4; ++i) {
      int row = rowbase + rt * 16 + lk * 4 + i;
      int rc = min(row, N - 1);
      nxr[rt][i] = (row < N) ? nxArr[rc] : 1e37f;
      qrow[rt][i] = (row < N) ? qArr[rc] : 0.f;
    }
  __syncthreads();

  float rep = 0.f;
  int obj0 = wv * 256 + lr;
  // prologue prefetch (tt = 0)
  short8 bcur = *(const short8*)(xkb + (size_t)obj0 * D + lk * 8);
  float2 qncur = qnkS[obj0];
#pragma unroll 2
  for (int tt = 0; tt < 16; ++tt) {
    // prefetch next iteration (wraps to tt=0 on the last — harmless re-read)
    int objn = obj0 + ((tt + 1) & 15) * 16;
    short8 bnext = *(const short8*)(xkb + (size_t)objn * D + lk * 8);
    float2 qnnext = qnkS[objn];

    float nk = qncur.y;
    f32x4 c0 = {nxr[0][0] + nk, nxr[0][1] + nk, nxr[0][2] + nk, nxr[0][3] + nk};
    f32x4 c1 = {nxr[1][0] + nk, nxr[1][1] + nk, nxr[1][2] + nk, nxr[1][3] + nk};
    f32x4 c2 = {nxr[2][0] + nk, nxr[2][1] + nk, nxr[2][2] + nk, nxr[2][3] + nk};
    f32x4 c3 = {nxr[3][0] + nk, nxr[3][1] + nk, nxr[3][2] + nk, nxr[3][3] + nk};
    f32x4 s0 = __builtin_amdgcn_mfma_f32_16x16x32_bf16(am2[0], bcur, c0, 0, 0, 0);
    f32x4 s1 = __builtin_amdgcn_mfma_f32_16x16x32_bf16(am2[1], bcur, c1, 0, 0, 0);
    f32x4 s2 = __builtin_amdgcn_mfma_f32_16x16x32_bf16(am2[2], bcur, c2, 0, 0, 0);
    f32x4 s3 = __builtin_amdgcn_mfma_f32_16x16x32_bf16(am2[3], bcur, c3, 0, 0, 0);
    float m = 1e30f;
#pragma unroll
    for (int i = 0; i < 4; ++i)
      m = fminf(m, fminf(fminf(s0[i], s1[i]), fminf(s2[i], s3[i])));
    if (__any(m < 1.f)) {  // rare: some pair within unit distance
      float qk = qncur.x;
#pragma unroll
      for (int rt = 0; rt < 4; ++rt) {
#pragma unroll
        for (int i = 0; i < 4; ++i) {
          float d2 = (rt == 0) ? s0[i] : (rt == 1) ? s1[i] : (rt == 2) ? s2[i] : s3[i];
          if (d2 < 1.f)
            rep += qrow[rt][i] * qk * (1.f - sqrtf(fmaxf(d2, 1e-12f)));
        }
      }
    }
    bcur = bnext;
    qncur = qnnext;
  }
  float sw = waveSum(rep);
  if (ln == 0 && sw != 0.f) atomicAdd(&acc[1], sw);

  // ---- exact f32 attractive term for this block's own 64 rows (wave 0) ----
  if (t < 64) {
    int j = rowbase + t;
    float attc = 0.f, repSub = 0.f;
    if (j < N) {
      int attk = attkArr[j];
      if (attk >= 1) {
        int k0 = attk - 1;
        int alpha = alphaArr[k0];
        float2 qn = qnk[k0];  // exact f32 (q_k, nx_k)
        const float4* xj = (const float4*)(x + (size_t)j * D);
        const float4* xk = (const float4*)(x + (size_t)alpha * D);
        float dot = 0.f;
#pragma unroll
        for (int i = 0; i < 8; ++i) {
          float4 a = xj[i], bb = xk[i];
          dot += a.x * bb.x + a.y * bb.y + a.z * bb.z + a.w * bb.w;
        }
        float d2 = nxArr[j] + qn.y - 2.f * dot;
        float w = qArr[j] * qn.x;
        attc = w * fmaxf(d2, 1e-12f);
        if (d2 < 1.f)  // att pair was counted by the rep sweep: subtract
          repSub = w * (1.f - sqrtf(fmaxf(d2, 1e-12f)));
      }
    }
    float sa = waveSum(attc);
    float sr = waveSum(repSub);
    if (t == 0) {
      if (sa != 0.f) atomicAdd(&acc[0], sa);
      if (sr != 0.f) atomicAdd(&acc[1], -sr);
    }
  }
}

__global__ void k_final(const float* __restrict__ acc, int N, float* out) {
  if (threadIdx.x == 0 && blockIdx.x == 0) {
    double attSum = acc[0], repSum = acc[1], noiseSum = acc[2];
    double noiseCnt = acc[3], okCnt = acc[4], cowardSum = acc[5];
    double norm_att = 1e-9 + okCnt - (double)KOBJ;
    double norm_rep = 1e-9 + (double)(KOBJ - 1) * (double)N;
    double v_att = attSum / norm_att;
    double v_rep = repSum / norm_rep;
    double l_coward = cowardSum / (double)KOBJ;
    double l_noise = noiseSum / fmax(noiseCnt, 1.0);
    out[0] = (float)(v_att + 1.0 * v_rep + 0.1 * l_noise + 0.1 * l_coward);
  }
}

}  // namespace

extern "C" void kernel_launch(void* const* d_in, const int* in_sizes, int n_in,
                              void* d_out, int out_size, void* d_ws, size_t ws_size,
                              hipStream_t stream) {
  const float* beta = (const float*)d_in[0];
  const float* x = (const float*)d_in[1];
  const float* pt = (const float*)d_in[2];
  const float* eta = (const float*)d_in[3];
  const int* recon = (const int*)d_in[4];
  const int* cidw = (const int*)d_in[5];  // int32 or int64 layout, device-detected
  int N = in_sizes[0];
  float* out = (float*)d_out;

  char* w = (char*)d_ws;
  float* acc = (float*)w;                                   // 8 f32
  int* flagNZ = (int*)(w + 40);
  unsigned long long* keys = (unsigned long long*)(w + 64); // 1023*8
  int* alphaArr = (int*)(w + 8256);                         // 1023*4
  float2* qnk = (float2*)(w + 12352);                       // 1024*8
  ushort* xkb = (ushort*)(w + 20544);                       // 1024*32*2 = 65536
  float* qArr = (float*)(w + 86080);                        // N*4
  float* nxArr = (float*)(w + 86080 + (size_t)N * 4);       // N*4
  int* attkArr = (int*)(w + 86080 + (size_t)N * 8);         // N*4

  int nbN = (N + 255) / 256;
  int rowgroups = (N + 63) / 64;

  k_init<<<4, 256, 0, stream>>>(acc, flagNZ, keys, cidw, N);
  k_hits<<<nbN, 256, 0, stream>>>(beta, x, pt, eta, recon, cidw, N, flagNZ,
                                  acc, keys, qArr, nxArr, attkArr);
  k_clusters<<<4, 256, 0, stream>>>(beta, x, keys, qArr, nxArr,
                                    alphaArr, qnk, xkb, acc);
  k_pair<<<rowgroups, 256, 0, stream>>>(x, N, qArr, nxArr, attkArr,
                                        alphaArr, qnk, xkb, acc);
  k_final<<<1, 64, 0, stream>>>(acc, N, out);
}